// Round 7
// baseline (166.861 us; speedup 1.0000x reference)
//
#include <hip/hip_runtime.h>
#include <math.h>

// Geodesic loss: mean over B of acos(clip((sum_ij m1*m2 - 1)*0.5, -1, 1)).
// R1-R6 lesson: two independent defeaters kept every variant at ~55us:
//  (a) __syncthreads() emits s_waitcnt vmcnt(0) before s_barrier -> drains
//      all prefetch (m97 lesson) -- any block-level LDS handoff loses;
//  (b) default __launch_bounds__ makes the scheduler target max occupancy
//      -> collapses 18-load batches to VGPR 32-52, ~1 load in flight.
// R7: wave-private LDS slices (9KB/wave) so the product regroup needs NO
// s_barrier (per-wave DS queue is in-order; wave_barrier() is compiler-only
// and emits no waitcnt), plus __launch_bounds__(256,4) (128-VGPR target:
// 18 live float4 fit). vmcnt is never drained inside the loop.

#define TPB 256
#define WPB 4                    // waves per block
#define MPW 256                  // matrices per wave-tile
#define F_PER_WTILE 2304         // floats per input per wave-tile (9*MPW)
#define F4_PER_WTILE 576         // float4 per input per wave-tile
#define NBLOCKS 1024             // 4 blocks/CU on 256 CUs (LDS-limited)

__global__ __launch_bounds__(TPB, 4) void geo_kernel(
    const float* __restrict__ a, const float* __restrict__ b,
    float* __restrict__ out, float invM, int M)
{
    __shared__ float prod[WPB * F_PER_WTILE];   // 36 KB, wave-private slices
    __shared__ float wsum[WPB];

    const int tid  = threadIdx.x;
    const int lane = tid & 63;
    const int wid  = tid >> 6;
    float* __restrict__ slice = prod + wid * F_PER_WTILE;
    float4* __restrict__ slice4 = (float4*)slice;

    const long long nwt = (long long)M / MPW;             // full wave-tiles
    const long long gw  = (long long)blockIdx.x * WPB + wid;
    const long long nw  = (long long)gridDim.x * WPB;

    float sum = 0.0f;

    for (long long t = gw; t < nwt; t += nw) {
        const float4* __restrict__ pa = (const float4*)a + t * F4_PER_WTILE + lane;
        const float4* __restrict__ pb = (const float4*)b + t * F4_PER_WTILE + lane;

        // 18 coalesced loads (each wave-instr = contiguous 1KB within the
        // wave's 9KB span). Named registers; issue all before first use.
        float4 A0 = pa[0],   A1 = pa[64],  A2 = pa[128], A3 = pa[192],
               A4 = pa[256], A5 = pa[320], A6 = pa[384], A7 = pa[448],
               A8 = pa[512];
        float4 B0 = pb[0],   B1 = pb[64],  B2 = pb[128], B3 = pb[192],
               B4 = pb[256], B5 = pb[320], B6 = pb[384], B7 = pb[448],
               B8 = pb[512];

        // Elementwise products into the wave-private slice. Each ds_write
        // waits fine-grained vmcnt(N) for its own pair only.
        #define PK(k)                                                       \
            {                                                               \
                float4 p;                                                   \
                p.x = A##k.x * B##k.x; p.y = A##k.y * B##k.y;               \
                p.z = A##k.z * B##k.z; p.w = A##k.w * B##k.w;               \
                slice4[k * 64 + lane] = p;                                  \
            }
        PK(0) PK(1) PK(2) PK(3) PK(4) PK(5) PK(6) PK(7) PK(8)
        #undef PK

        // Same-wave write->read: DS queue is in-order per wave; this only
        // pins compiler ordering. Emits NO instruction, drains NO counter.
        __builtin_amdgcn_wave_barrier();

        // Regroup: lane owns matrices {lane, lane+64, lane+128, lane+192}.
        // Lane stride 9 floats (odd) -> 2 lanes/bank -> conflict-free.
        #pragma unroll
        for (int c = 0; c < 4; ++c) {
            const int base = 9 * (lane + 64 * c);
            float d = ((slice[base + 0] + slice[base + 1]) +
                       (slice[base + 2] + slice[base + 3])) +
                      ((slice[base + 4] + slice[base + 5]) +
                       (slice[base + 6] + slice[base + 7])) + slice[base + 8];
            float cv = fminf(1.0f, fmaxf(-1.0f, (d - 1.0f) * 0.5f));
            sum += acosf(cv);
        }
        __builtin_amdgcn_wave_barrier();  // WAR: next tile's writes stay after reads
    }

    // tail matrices beyond the last full wave-tile (empty for B=2^21)
    {
        const long long gid    = (long long)blockIdx.x * TPB + tid;
        const long long stride = (long long)gridDim.x * TPB;
        for (long long m = nwt * MPW + gid; m < M; m += stride) {
            float d = 0.0f;
            for (int j = 0; j < 9; ++j)
                d = fmaf(a[m * 9 + j], b[m * 9 + j], d);
            float cv = fminf(1.0f, fmaxf(-1.0f, (d - 1.0f) * 0.5f));
            sum += acosf(cv);
        }
    }

    // wave shuffle reduce -> per-block LDS reduce -> one atomic per block
    #pragma unroll
    for (int off = 32; off > 0; off >>= 1)
        sum += __shfl_down(sum, off, 64);
    if (lane == 0) wsum[wid] = sum;
    __syncthreads();   // only barrier in the kernel, after all streaming
    if (tid == 0) {
        float s = 0.0f;
        #pragma unroll
        for (int i = 0; i < WPB; ++i) s += wsum[i];
        atomicAdd(out, s * invM);   // device-scope by default
    }
}

extern "C" void kernel_launch(void* const* d_in, const int* in_sizes, int n_in,
                              void* d_out, int out_size, void* d_ws, size_t ws_size,
                              hipStream_t stream) {
    const float* a = (const float*)d_in[0];
    const float* b = (const float*)d_in[1];
    float* out = (float*)d_out;

    const int n = in_sizes[0];   // flat float count = 9*M
    const int M = n / 9;         // number of 3x3 matrices

    // d_out is re-poisoned 0xAA before every timed launch; zero it (async,
    // graph-capture safe), then accumulate the mean with per-block atomics.
    hipMemsetAsync(out, 0, (size_t)out_size * sizeof(float), stream);
    geo_kernel<<<NBLOCKS, TPB, 0, stream>>>(a, b, out, 1.0f / (float)M, M);
}